// Round 3
// baseline (4891.031 us; speedup 1.0000x reference)
//
#include <hip/hip_runtime.h>
#include <hip/hip_bf16.h>
#include <math.h>

typedef __hip_bfloat16 bf16;
typedef __attribute__((ext_vector_type(8))) short short8;
typedef __attribute__((ext_vector_type(4))) float f32x4;

#define HID 256
#define PRED 16
#define MNODES 4096
#define NLEV 16
#define NTOT (NLEV*MNODES)
#define LN_EPS 1e-5f

__device__ inline float b2f(bf16 v) { return __bfloat162float(v); }
__device__ inline float su2f(short s) { return __uint_as_float(((unsigned)(unsigned short)s) << 16); }
__device__ inline bf16 f2b(float f) { return __float2bfloat16(f); }
__device__ inline short f2bs(float f) { bf16 b = __float2bfloat16(f); return *reinterpret_cast<short*>(&b); }

// read element i of a float array that is either f32 (f=1) or bf16 (f=0)
__device__ inline float ldf(const void* p, size_t i, int f) {
    return f ? ((const float*)p)[i] : b2f(((const bf16*)p)[i]);
}

// split 8 consecutive f32 (32B-aligned) into hi/lo bf16 fragments
__device__ inline void split8_f32(const float* p, short8& hi, short8& lo) {
    f32x4 a = *(const f32x4*)(const void*)p;
    f32x4 b = *(const f32x4*)(const void*)(p + 4);
    #pragma unroll
    for (int e = 0; e < 4; e++) { short h = f2bs(a[e]); hi[e] = h; lo[e] = f2bs(a[e] - su2f(h)); }
    #pragma unroll
    for (int e = 0; e < 4; e++) { short h = f2bs(b[e]); hi[4+e] = h; lo[4+e] = f2bs(b[e] - su2f(h)); }
}

// load 8 elems from dual-dtype global array, produce hi/lo bf16 fragments
__device__ inline void load_split8(const void* base, size_t off, int f, short8& hi, short8& lo) {
    if (f) {
        split8_f32((const float*)base + off, hi, lo);
    } else {
        hi = *(const short8*)(const void*)((const bf16*)base + off);
        lo = short8{0,0,0,0,0,0,0,0};
    }
}

// ---------------------------------------------------------------------------
// dtype detection: count uint16 words of x whose bf16-exponent field is in a
// plausible normal range.  bf16 data -> ~512/512; f32 data -> ~296/512.
// ---------------------------------------------------------------------------
__global__ void detect_dtype(const unsigned short* __restrict__ x, int* __restrict__ flag)
{
    __shared__ int cnt;
    if (threadIdx.x == 0) cnt = 0;
    __syncthreads();
    int c = 0;
    for (int i = threadIdx.x; i < 512; i += 256) {
        int e = (x[i] >> 7) & 0xFF;
        if (e >= 100 && e <= 140) c++;
    }
    atomicAdd(&cnt, c);
    __syncthreads();
    if (threadIdx.x == 0) *flag = (cnt >= 480) ? 0 : 1;   // 0 = bf16, 1 = f32
}

// ---------------------------------------------------------------------------
// convert inputs: split matrices to hi/lo bf16; vectors to f32
// ---------------------------------------------------------------------------
struct CD { const void* src; bf16* dhi; bf16* dlo; float* dfp; int n; int kind; };
struct CA { CD d[10]; };

__global__ void convert_in(CA a, const int* __restrict__ flagp)
{
    const int f = *flagp;
    CD d = a.d[blockIdx.y];
    int i = (blockIdx.x * 256 + threadIdx.x) * 8;
    if (i >= d.n) return;
    if (d.kind == 0) {
        if (f) {
            const float* s = (const float*)d.src + i;
            #pragma unroll
            for (int e = 0; e < 8; e++) {
                float v = s[e]; bf16 h = f2b(v);
                d.dhi[i+e] = h; d.dlo[i+e] = f2b(v - b2f(h));
            }
        } else {
            const bf16* s = (const bf16*)d.src + i;
            #pragma unroll
            for (int e = 0; e < 8; e++) { d.dhi[i+e] = s[e]; d.dlo[i+e] = f2b(0.f); }
        }
    } else {
        #pragma unroll
        for (int e = 0; e < 8; e++) d.dfp[i+e] = ldf(d.src, i+e, f);
    }
}

// ---------------------------------------------------------------------------
// Wcomb = [Wc1 | Wc2@Wo] (split hi/lo), beff = bc + Wc2@bo   (f32 compute)
// ---------------------------------------------------------------------------
__global__ void build_wcomb(const void* __restrict__ Wc, const void* __restrict__ Wo,
                            const void* __restrict__ bo, const void* __restrict__ bc,
                            bf16* __restrict__ WcombHi, bf16* __restrict__ WcombLo,
                            float* __restrict__ beff, const int* __restrict__ flagp)
{
    const int f = *flagp;
    const int l = blockIdx.y, o = blockIdx.x, j = threadIdx.x;
    __shared__ float wcs[HID];
    const size_t rowc = (size_t)(l*HID + o) * 512;
    wcs[j] = ldf(Wc, rowc + HID + j, f);
    float c1 = ldf(Wc, rowc + j, f);
    { bf16 h = f2b(c1); WcombHi[rowc + j] = h; WcombLo[rowc + j] = f2b(c1 - b2f(h)); }
    __syncthreads();
    const size_t wbase = (size_t)l * HID * HID;
    float s = 0.f;
    for (int k = 0; k < HID; k++) s += wcs[k] * ldf(Wo, wbase + (size_t)k*HID + j, f);
    { bf16 h = f2b(s); WcombHi[rowc + HID + j] = h; WcombLo[rowc + HID + j] = f2b(s - b2f(h)); }
    if (j == 0) {
        float b = 0.f;
        for (int k = 0; k < HID; k++) b += wcs[k] * ldf(bo, l*HID + k, f);
        beff[l*HID + o] = b + ldf(bc, l*HID + o, f);
    }
}

// ---------------------------------------------------------------------------
// split-bf16 GEMM: C[rows,256] = A[rows,256(@lda)] @ W^T + bias
// A dual-dtype (flag); W pre-split hi/lo [256][256]; C: cmode 0 = f32 ws,
// cmode 1 = dual-dtype (d_out)
// ---------------------------------------------------------------------------
#define GBK 32
#define GPAD 8

__global__ __launch_bounds__(256) void gemm_split(
    const void* __restrict__ Abase, size_t aoff, int lda,
    const bf16* __restrict__ Whi, const bf16* __restrict__ Wlo,
    const float* __restrict__ biasF,
    void* __restrict__ Cbase, size_t coff, int ldc, int cmode,
    const int* __restrict__ flagp)
{
    __shared__ short Ahi[128][GBK + GPAD], Alo[128][GBK + GPAD];
    __shared__ short Bhi[128][GBK + GPAD], Blo[128][GBK + GPAD];
    const int f = *flagp;
    const int tid  = threadIdx.x;
    const int lane = tid & 63;
    const int wave = tid >> 6;
    const int row0 = blockIdx.x * 128;
    const int col0 = blockIdx.y * 128;
    const int wr = (wave >> 1) * 64;
    const int wc = (wave & 1) * 64;
    const int q4  = lane >> 4;
    const int m16 = lane & 15;

    f32x4 acc[4][4];
    #pragma unroll
    for (int i = 0; i < 4; i++)
        #pragma unroll
        for (int j = 0; j < 4; j++)
            acc[i][j] = (f32x4){0.f,0.f,0.f,0.f};

    const int r0s = tid >> 2, s0s = tid & 3;   // rows 0..63
    const int r1s = r0s + 64;

    for (int k0 = 0; k0 < 256; k0 += GBK) {
        short8 h0, l0, h1, l1;
        load_split8(Abase, aoff + (size_t)(row0 + r0s)*lda + k0 + s0s*8, f, h0, l0);
        load_split8(Abase, aoff + (size_t)(row0 + r1s)*lda + k0 + s0s*8, f, h1, l1);
        *(short8*)&Ahi[r0s][s0s*8] = h0;  *(short8*)&Alo[r0s][s0s*8] = l0;
        *(short8*)&Ahi[r1s][s0s*8] = h1;  *(short8*)&Alo[r1s][s0s*8] = l1;
        *(short8*)&Bhi[r0s][s0s*8] = *(const short8*)(const void*)(Whi + (size_t)(col0 + r0s)*256 + k0 + s0s*8);
        *(short8*)&Blo[r0s][s0s*8] = *(const short8*)(const void*)(Wlo + (size_t)(col0 + r0s)*256 + k0 + s0s*8);
        *(short8*)&Bhi[r1s][s0s*8] = *(const short8*)(const void*)(Whi + (size_t)(col0 + r1s)*256 + k0 + s0s*8);
        *(short8*)&Blo[r1s][s0s*8] = *(const short8*)(const void*)(Wlo + (size_t)(col0 + r1s)*256 + k0 + s0s*8);
        __syncthreads();
        short8 ah[4], al[4], bh[4], bl[4];
        #pragma unroll
        for (int i = 0; i < 4; i++) {
            ah[i] = *(const short8*)&Ahi[wr + i*16 + m16][q4*8];
            al[i] = *(const short8*)&Alo[wr + i*16 + m16][q4*8];
        }
        #pragma unroll
        for (int j = 0; j < 4; j++) {
            bh[j] = *(const short8*)&Bhi[wc + j*16 + m16][q4*8];
            bl[j] = *(const short8*)&Blo[wc + j*16 + m16][q4*8];
        }
        #pragma unroll
        for (int i = 0; i < 4; i++)
            #pragma unroll
            for (int j = 0; j < 4; j++) {
                acc[i][j] = __builtin_amdgcn_mfma_f32_16x16x32_bf16(ah[i], bh[j], acc[i][j], 0, 0, 0);
                acc[i][j] = __builtin_amdgcn_mfma_f32_16x16x32_bf16(ah[i], bl[j], acc[i][j], 0, 0, 0);
                acc[i][j] = __builtin_amdgcn_mfma_f32_16x16x32_bf16(al[i], bh[j], acc[i][j], 0, 0, 0);
            }
        __syncthreads();
    }
    const bool outf32 = (cmode == 0) || f;
    #pragma unroll
    for (int j = 0; j < 4; j++) {
        int col = col0 + wc + j*16 + m16;
        float bj = biasF[col];
        #pragma unroll
        for (int i = 0; i < 4; i++)
            #pragma unroll
            for (int r = 0; r < 4; r++) {
                int row = row0 + wr + i*16 + q4*4 + r;
                float v = acc[i][j][r] + bj;
                if (outf32) ((float*)Cbase)[coff + (size_t)row*ldc + col] = v;
                else        ((bf16*)Cbase)[coff + (size_t)row*ldc + col] = f2b(v);
            }
    }
}

// out[r, 256..1024) = out[r, 0..256) for rows r < M
__global__ void replicate_l0(void* __restrict__ out, const int* __restrict__ flagp)
{
    const int f = *flagp;
    int idx = (blockIdx.x * 256 + threadIdx.x) * 8;   // over M*768 elems
    int r = idx / 768, c = idx % 768;
    if (f) {
        float* o = (float*)out;
        f32x4 a = *(const f32x4*)(const void*)(o + (size_t)r*1024 + (c & 255));
        f32x4 b = *(const f32x4*)(const void*)(o + (size_t)r*1024 + (c & 255) + 4);
        *(f32x4*)(void*)(o + (size_t)r*1024 + 256 + c)     = a;
        *(f32x4*)(void*)(o + (size_t)r*1024 + 256 + c + 4) = b;
    } else {
        bf16* o = (bf16*)out;
        *(short8*)(void*)(o + (size_t)r*1024 + 256 + c) =
            *(const short8*)(const void*)(o + (size_t)r*1024 + (c & 255));
    }
}

// ---------------------------------------------------------------------------
// Fused per-level step (f32 attention + split-bf16 MFMA GEMMs)
// ---------------------------------------------------------------------------
#define SR 32
#define LROW (HID + 8)

__global__ __launch_bounds__(256) void step_fused(
    const float* __restrict__ Qlv,     // [M,256] f32, level-local
    const void*  __restrict__ outb, size_t qoff, size_t hoff,
    const int*   __restrict__ plv, int predbase,
    const float* __restrict__ Kin, const float* __restrict__ Vin,   // [M,256] f32
    const bf16* __restrict__ WcHi, const bf16* __restrict__ WcLo,   // [256][512]
    const float* __restrict__ beff,
    const float* __restrict__ lngF, const float* __restrict__ lnbF,
    const bf16* __restrict__ WkHi, const bf16* __restrict__ WkLo, const float* __restrict__ bkF,
    const bf16* __restrict__ WvHi, const bf16* __restrict__ WvLo, const float* __restrict__ bvF,
    float* __restrict__ Kout, float* __restrict__ Vout,
    int do_kv, const int* __restrict__ flagp)
{
    // smem: phase A writes agg (f32); phase B output z aliases it; LN/GELU in place.
    __shared__ __align__(16) float smem[SR][LROW];

    const int f = *flagp;
    const int tid  = threadIdx.x;
    const int lane = tid & 63;
    const int wave = tid >> 6;
    const int jbase = blockIdx.x * SR;
    const int q4  = lane >> 4;
    const int m16 = lane & 15;
    const int cw  = wave * 64;

    // ---- Phase A: f32 attention. 2 threads per (row, head), 8 preds each ----
    {
        const int rh = tid >> 1, half = tid & 1;
        const int r = rh >> 2, h = rh & 3;
        const int j = jbase + r;

        float qf[64];
        const f32x4* qv = (const f32x4*)(const void*)(Qlv + (size_t)j*HID + h*64);
        #pragma unroll
        for (int s = 0; s < 16; s++) {
            f32x4 v = qv[s];
            qf[s*4+0]=v[0]; qf[s*4+1]=v[1]; qf[s*4+2]=v[2]; qf[s*4+3]=v[3];
        }
        int pl[8];
        #pragma unroll
        for (int p = 0; p < 8; p++)
            pl[p] = (plv[(size_t)j*PRED + half*8 + p] - predbase) & (MNODES-1);

        float sc[8];
        #pragma unroll
        for (int p = 0; p < 8; p++) {
            const f32x4* kv = (const f32x4*)(const void*)(Kin + (size_t)pl[p]*HID + h*64);
            float s = 0.f;
            #pragma unroll
            for (int sg = 0; sg < 16; sg++) {
                f32x4 v = kv[sg];
                s += qf[sg*4+0]*v[0] + qf[sg*4+1]*v[1] + qf[sg*4+2]*v[2] + qf[sg*4+3]*v[3];
            }
            sc[p] = s * 0.125f;
        }
        float mx = sc[0];
        #pragma unroll
        for (int p = 1; p < 8; p++) mx = fmaxf(mx, sc[p]);
        mx = fmaxf(mx, __shfl_xor(mx, 1));
        float den = 0.f;
        #pragma unroll
        for (int p = 0; p < 8; p++) { sc[p] = __expf(sc[p] - mx); den += sc[p]; }
        den += __shfl_xor(den, 1);
        float inv = 1.f / den;

        float ag[64];
        #pragma unroll
        for (int d = 0; d < 64; d++) ag[d] = 0.f;
        #pragma unroll
        for (int p = 0; p < 8; p++) {
            float wgt = sc[p] * inv;
            const f32x4* vv = (const f32x4*)(const void*)(Vin + (size_t)pl[p]*HID + h*64);
            #pragma unroll
            for (int sg = 0; sg < 16; sg++) {
                f32x4 v = vv[sg];
                ag[sg*4+0] += wgt*v[0]; ag[sg*4+1] += wgt*v[1];
                ag[sg*4+2] += wgt*v[2]; ag[sg*4+3] += wgt*v[3];
            }
        }
        #pragma unroll
        for (int d = 0; d < 64; d++) ag[d] += __shfl_xor(ag[d], 1);
        if (half == 0) {
            #pragma unroll
            for (int d = 0; d < 64; d++) smem[r][h*64 + d] = ag[d];
        }
    }
    __syncthreads();

    // ---- Phase B: acc = [q|agg] @ Wcomb^T  (32x256, K=512, split-bf16) ----
    f32x4 accB[2][4];
    #pragma unroll
    for (int i = 0; i < 2; i++)
        #pragma unroll
        for (int jj = 0; jj < 4; jj++)
            accB[i][jj] = (f32x4){0.f,0.f,0.f,0.f};

    #pragma unroll
    for (int kk = 0; kk < 8; kk++) {          // q half (from global prev rows)
        short8 ah[2], al[2], bh[4], bl[4];
        #pragma unroll
        for (int i = 0; i < 2; i++)
            load_split8(outb, qoff + (size_t)(jbase + i*16 + m16)*1024 + kk*32 + q4*8, f, ah[i], al[i]);
        #pragma unroll
        for (int jj = 0; jj < 4; jj++) {
            bh[jj] = *(const short8*)(const void*)(WcHi + (size_t)(cw + jj*16 + m16)*512 + kk*32 + q4*8);
            bl[jj] = *(const short8*)(const void*)(WcLo + (size_t)(cw + jj*16 + m16)*512 + kk*32 + q4*8);
        }
        #pragma unroll
        for (int i = 0; i < 2; i++)
            #pragma unroll
            for (int jj = 0; jj < 4; jj++) {
                accB[i][jj] = __builtin_amdgcn_mfma_f32_16x16x32_bf16(ah[i], bh[jj], accB[i][jj], 0, 0, 0);
                accB[i][jj] = __builtin_amdgcn_mfma_f32_16x16x32_bf16(ah[i], bl[jj], accB[i][jj], 0, 0, 0);
                accB[i][jj] = __builtin_amdgcn_mfma_f32_16x16x32_bf16(al[i], bh[jj], accB[i][jj], 0, 0, 0);
            }
    }
    #pragma unroll
    for (int kk = 0; kk < 8; kk++) {          // agg half (from smem f32)
        short8 ah[2], al[2], bh[4], bl[4];
        #pragma unroll
        for (int i = 0; i < 2; i++)
            split8_f32(&smem[i*16 + m16][kk*32 + q4*8], ah[i], al[i]);
        #pragma unroll
        for (int jj = 0; jj < 4; jj++) {
            bh[jj] = *(const short8*)(const void*)(WcHi + (size_t)(cw + jj*16 + m16)*512 + 256 + kk*32 + q4*8);
            bl[jj] = *(const short8*)(const void*)(WcLo + (size_t)(cw + jj*16 + m16)*512 + 256 + kk*32 + q4*8);
        }
        #pragma unroll
        for (int i = 0; i < 2; i++)
            #pragma unroll
            for (int jj = 0; jj < 4; jj++) {
                accB[i][jj] = __builtin_amdgcn_mfma_f32_16x16x32_bf16(ah[i], bh[jj], accB[i][jj], 0, 0, 0);
                accB[i][jj] = __builtin_amdgcn_mfma_f32_16x16x32_bf16(ah[i], bl[jj], accB[i][jj], 0, 0, 0);
                accB[i][jj] = __builtin_amdgcn_mfma_f32_16x16x32_bf16(al[i], bh[jj], accB[i][jj], 0, 0, 0);
            }
    }
    __syncthreads();   // agg region dead; reuse smem for z

    #pragma unroll
    for (int jj = 0; jj < 4; jj++) {
        int col = cw + jj*16 + m16;
        float be = beff[col];
        #pragma unroll
        for (int i = 0; i < 2; i++)
            #pragma unroll
            for (int r = 0; r < 4; r++)
                smem[i*16 + q4*4 + r][col] = accB[i][jj][r] + be;
    }
    __syncthreads();

    // ---- Phase C: LayerNorm + GELU, in place (8 threads/row) ----
    {
        const int rr = tid >> 3;
        const int g  = tid & 7;
        float sum = 0.f, sq = 0.f;
        #pragma unroll
        for (int c = 0; c < 32; c++) {
            float z = smem[rr][g + 8*c];
            sum += z; sq += z*z;
        }
        sum += __shfl_xor(sum, 1); sq += __shfl_xor(sq, 1);
        sum += __shfl_xor(sum, 2); sq += __shfl_xor(sq, 2);
        sum += __shfl_xor(sum, 4); sq += __shfl_xor(sq, 4);
        float mean = sum * (1.f/256.f);
        float var  = fmaxf(sq * (1.f/256.f) - mean*mean, 0.f);
        float rstd = rsqrtf(var + LN_EPS);
        #pragma unroll
        for (int c = 0; c < 32; c++) {
            int col = g + 8*c;
            float zn = (smem[rr][col] - mean) * rstd * lngF[col] + lnbF[col];
            smem[rr][col] = 0.5f * zn * (1.f + erff(zn * 0.70710678118f));
        }
    }
    __syncthreads();

    // ---- store h ----
    {
        const int rr = tid >> 3;
        const int g  = tid & 7;
        if (f) {
            float* dst = (float*)outb + hoff + (size_t)(jbase + rr)*1024 + g*32;
            #pragma unroll
            for (int s = 0; s < 8; s++)
                *(f32x4*)(void*)(dst + s*4) = *(const f32x4*)(const void*)&smem[rr][g*32 + s*4];
        } else {
            bf16* dst = (bf16*)outb + hoff + (size_t)(jbase + rr)*1024 + g*32;
            #pragma unroll
            for (int s = 0; s < 4; s++) {
                short8 o;
                #pragma unroll
                for (int e = 0; e < 8; e++) o[e] = f2bs(smem[rr][g*32 + s*8 + e]);
                *(short8*)(void*)(dst + s*8) = o;
            }
        }
    }

    // ---- Phase D: next-level K/V (split-bf16 MFMA), f32 out ----
    if (do_kv) {
        #pragma unroll
        for (int pass = 0; pass < 2; pass++) {
            const bf16* Wph = pass ? WvHi : WkHi;
            const bf16* Wpl = pass ? WvLo : WkLo;
            const float* bp = pass ? bvF : bkF;
            float* Op = pass ? Vout : Kout;
            f32x4 acc[2][4];
            #pragma unroll
            for (int i = 0; i < 2; i++)
                #pragma unroll
                for (int jj = 0; jj < 4; jj++)
                    acc[i][jj] = (f32x4){0.f,0.f,0.f,0.f};
            #pragma unroll
            for (int kk = 0; kk < 8; kk++) {
                short8 ah[2], al[2], bh[4], bl[4];
                #pragma unroll
                for (int i = 0; i < 2; i++)
                    split8_f32(&smem[i*16 + m16][kk*32 + q4*8], ah[i], al[i]);
                #pragma unroll
                for (int jj = 0; jj < 4; jj++) {
                    bh[jj] = *(const short8*)(const void*)(Wph + (size_t)(cw + jj*16 + m16)*256 + kk*32 + q4*8);
                    bl[jj] = *(const short8*)(const void*)(Wpl + (size_t)(cw + jj*16 + m16)*256 + kk*32 + q4*8);
                }
                #pragma unroll
                for (int i = 0; i < 2; i++)
                    #pragma unroll
                    for (int jj = 0; jj < 4; jj++) {
                        acc[i][jj] = __builtin_amdgcn_mfma_f32_16x16x32_bf16(ah[i], bh[jj], acc[i][jj], 0, 0, 0);
                        acc[i][jj] = __builtin_amdgcn_mfma_f32_16x16x32_bf16(ah[i], bl[jj], acc[i][jj], 0, 0, 0);
                        acc[i][jj] = __builtin_amdgcn_mfma_f32_16x16x32_bf16(al[i], bh[jj], acc[i][jj], 0, 0, 0);
                    }
            }
            #pragma unroll
            for (int jj = 0; jj < 4; jj++) {
                int col = cw + jj*16 + m16;
                float bb = bp[col];
                #pragma unroll
                for (int i = 0; i < 2; i++)
                    #pragma unroll
                    for (int r = 0; r < 4; r++)
                        Op[(size_t)(jbase + i*16 + q4*4 + r)*HID + col] = acc[i][jj][r] + bb;
            }
        }
    }
}

// ---------------------------------------------------------------------------
extern "C" void kernel_launch(void* const* d_in, const int* in_sizes, int n_in,
                              void* d_out, int out_size, void* d_ws, size_t ws_size,
                              hipStream_t stream)
{
    (void)in_sizes; (void)n_in; (void)out_size; (void)ws_size;
    const void* x    = d_in[0];
    const int* preds = (const int*)d_in[3];
    const void* W_in = d_in[4];  const void* b_in = d_in[5];
    const void* Wq   = d_in[6];  const void* bq   = d_in[7];
    const void* Wk   = d_in[8];  const void* bk   = d_in[9];
    const void* Wv   = d_in[10]; const void* bv   = d_in[11];
    const void* Wo   = d_in[12]; const void* bo   = d_in[13];
    const void* Wc   = d_in[14]; const void* bc   = d_in[15];
    const void* lng  = d_in[16]; const void* lnb  = d_in[17];

    char* w = (char*)d_ws;
    #define TAKE(T, nbytes) (T*)w; w += (((size_t)(nbytes)) + 255) & ~(size_t)255
    int*   flag  = TAKE(int,   4);
    float* beff  = TAKE(float, 3*HID*4);
    float* binF  = TAKE(float, HID*4);
    float* bqF   = TAKE(float, 3*HID*4);
    float* bkF   = TAKE(float, 3*HID*4);
    float* bvF   = TAKE(float, 3*HID*4);
    float* lngF  = TAKE(float, 3*HID*4);
    float* lnbF  = TAKE(float, 3*HID*4);
    bf16* WinHi  = TAKE(bf16, 65536*2);   bf16* WinLo = TAKE(bf16, 65536*2);
    bf16* WqHi   = TAKE(bf16, 196608*2);  bf16* WqLo  = TAKE(bf16, 196608*2);
    bf16* WkHi   = TAKE(bf16, 196608*2);  bf16* WkLo  = TAKE(bf16, 196608*2);
    bf16* WvHi   = TAKE(bf16, 196608*2);  bf16* WvLo  = TAKE(bf16, 196608*2);
    bf16* WcombHi= TAKE(bf16, 393216*2);  bf16* WcombLo = TAKE(bf16, 393216*2);
    float* Kb0   = TAKE(float, (size_t)MNODES*HID*4);
    float* Kb1   = TAKE(float, (size_t)MNODES*HID*4);
    float* Vb0   = TAKE(float, (size_t)MNODES*HID*4);
    float* Vb1   = TAKE(float, (size_t)MNODES*HID*4);
    float* Qall  = TAKE(float, (size_t)(NTOT-MNODES)*HID*4);
    #undef TAKE
    float* Kb[2] = {Kb0, Kb1};
    float* Vb[2] = {Vb0, Vb1};

    detect_dtype<<<1, 256, 0, stream>>>((const unsigned short*)x, flag);

    CA ca;
    ca.d[0] = {W_in, WinHi, WinLo, nullptr, 65536, 0};
    ca.d[1] = {Wq,   WqHi,  WqLo,  nullptr, 196608, 0};
    ca.d[2] = {Wk,   WkHi,  WkLo,  nullptr, 196608, 0};
    ca.d[3] = {Wv,   WvHi,  WvLo,  nullptr, 196608, 0};
    ca.d[4] = {b_in, nullptr, nullptr, binF, 256, 1};
    ca.d[5] = {bq,   nullptr, nullptr, bqF,  768, 1};
    ca.d[6] = {bk,   nullptr, nullptr, bkF,  768, 1};
    ca.d[7] = {bv,   nullptr, nullptr, bvF,  768, 1};
    ca.d[8] = {lng,  nullptr, nullptr, lngF, 768, 1};
    ca.d[9] = {lnb,  nullptr, nullptr, lnbF, 768, 1};
    convert_in<<<dim3(96, 10), 256, 0, stream>>>(ca, flag);

    build_wcomb<<<dim3(HID, 3), 256, 0, stream>>>(Wc, Wo, bo, bc, WcombHi, WcombLo, beff, flag);

    // input projection -> out chunk 0
    gemm_split<<<dim3(NTOT/128, 2), 256, 0, stream>>>(x, 0, HID, WinHi, WinLo, binF,
                                                      d_out, 0, 1024, 1, flag);
    replicate_l0<<<(MNODES*768/8)/256, 256, 0, stream>>>(d_out, flag);

    for (int l = 0; l < 3; l++) {
        size_t prevOff = (size_t)MNODES*1024 + (size_t)l*HID;
        gemm_split<<<dim3((NTOT-MNODES)/128, 2), 256, 0, stream>>>(
            d_out, prevOff, 1024, WqHi + (size_t)l*65536, WqLo + (size_t)l*65536,
            bqF + l*HID, Qall, 0, HID, 0, flag);
        gemm_split<<<dim3(MNODES/128, 2), 256, 0, stream>>>(
            d_out, 0, 1024, WkHi + (size_t)l*65536, WkLo + (size_t)l*65536,
            bkF + l*HID, Kb0, 0, HID, 0, flag);
        gemm_split<<<dim3(MNODES/128, 2), 256, 0, stream>>>(
            d_out, 0, 1024, WvHi + (size_t)l*65536, WvLo + (size_t)l*65536,
            bvF + l*HID, Vb0, 0, HID, 0, flag);

        for (int lv = 0; lv < 15; lv++) {
            step_fused<<<MNODES/SR, 256, 0, stream>>>(
                Qall + (size_t)lv*MNODES*HID,
                d_out,
                (size_t)(lv+1)*MNODES*1024 + (size_t)l*HID,
                (size_t)(lv+1)*MNODES*1024 + (size_t)(l+1)*HID,
                preds + (size_t)lv*MNODES*PRED, lv*MNODES,
                Kb[lv & 1], Vb[lv & 1],
                WcombHi + (size_t)l*131072, WcombLo + (size_t)l*131072, beff + l*HID,
                lngF + l*HID, lnbF + l*HID,
                WkHi + (size_t)l*65536, WkLo + (size_t)l*65536, bkF + l*HID,
                WvHi + (size_t)l*65536, WvLo + (size_t)l*65536, bvF + l*HID,
                Kb[(lv+1) & 1], Vb[(lv+1) & 1],
                (lv < 14) ? 1 : 0, flag);
        }
    }
}

// Round 4
// 2669.080 us; speedup vs baseline: 1.8325x; 1.8325x over previous
//
#include <hip/hip_runtime.h>
#include <hip/hip_bf16.h>
#include <math.h>

typedef __hip_bfloat16 bf16;
typedef __attribute__((ext_vector_type(8))) short short8;
typedef __attribute__((ext_vector_type(4))) float f32x4;

#define HID 256
#define PRED 16
#define MNODES 4096
#define NLEV 16
#define NTOT (NLEV*MNODES)
#define LN_EPS 1e-5f

__device__ inline float b2f(bf16 v) { return __bfloat162float(v); }
__device__ inline float su2f(short s) { return __uint_as_float(((unsigned)(unsigned short)s) << 16); }
__device__ inline bf16 f2b(float f) { return __float2bfloat16(f); }
__device__ inline short f2bs(float f) { bf16 b = __float2bfloat16(f); return *reinterpret_cast<short*>(&b); }

__device__ inline float ldf(const void* p, size_t i, int f) {
    return f ? ((const float*)p)[i] : b2f(((const bf16*)p)[i]);
}

// split 8 consecutive f32 (16B-aligned) into hi/lo bf16 fragments
__device__ inline void split8_f32(const float* p, short8& hi, short8& lo) {
    f32x4 a = *(const f32x4*)(const void*)p;
    f32x4 b = *(const f32x4*)(const void*)(p + 4);
    #pragma unroll
    for (int e = 0; e < 4; e++) { short h = f2bs(a[e]); hi[e] = h; lo[e] = f2bs(a[e] - su2f(h)); }
    #pragma unroll
    for (int e = 0; e < 4; e++) { short h = f2bs(b[e]); hi[4+e] = h; lo[4+e] = f2bs(b[e] - su2f(h)); }
}

__device__ inline void load_split8(const void* base, size_t off, int f, short8& hi, short8& lo) {
    if (f) {
        split8_f32((const float*)base + off, hi, lo);
    } else {
        hi = *(const short8*)(const void*)((const bf16*)base + off);
        lo = short8{0,0,0,0,0,0,0,0};
    }
}

// ---------------------------------------------------------------------------
// dtype detection (bf16 vs f32) from exponent-field statistics of x
// ---------------------------------------------------------------------------
__global__ void detect_dtype(const unsigned short* __restrict__ x, int* __restrict__ flag)
{
    __shared__ int cnt;
    if (threadIdx.x == 0) cnt = 0;
    __syncthreads();
    int c = 0;
    for (int i = threadIdx.x; i < 512; i += 256) {
        int e = (x[i] >> 7) & 0xFF;
        if (e >= 100 && e <= 140) c++;
    }
    atomicAdd(&cnt, c);
    __syncthreads();
    if (threadIdx.x == 0) *flag = (cnt >= 480) ? 0 : 1;   // 0 = bf16, 1 = f32
}

// ---------------------------------------------------------------------------
// convert inputs: split matrices to hi/lo bf16; vectors to f32
// ---------------------------------------------------------------------------
struct CD { const void* src; bf16* dhi; bf16* dlo; float* dfp; int n; int kind; };
struct CA { CD d[10]; };

__global__ void convert_in(CA a, const int* __restrict__ flagp)
{
    const int f = *flagp;
    CD d = a.d[blockIdx.y];
    int i = (blockIdx.x * 256 + threadIdx.x) * 8;
    if (i >= d.n) return;
    if (d.kind == 0) {
        if (f) {
            const float* s = (const float*)d.src + i;
            #pragma unroll
            for (int e = 0; e < 8; e++) {
                float v = s[e]; bf16 h = f2b(v);
                d.dhi[i+e] = h; d.dlo[i+e] = f2b(v - b2f(h));
            }
        } else {
            const bf16* s = (const bf16*)d.src + i;
            #pragma unroll
            for (int e = 0; e < 8; e++) { d.dhi[i+e] = s[e]; d.dlo[i+e] = f2b(0.f); }
        }
    } else {
        #pragma unroll
        for (int e = 0; e < 8; e++) d.dfp[i+e] = ldf(d.src, i+e, f);
    }
}

// ---------------------------------------------------------------------------
// Wcomb = [Wc1 | Wc2@Wo] (split hi/lo), beff = bc + Wc2@bo   (f32 compute)
// ---------------------------------------------------------------------------
__global__ void build_wcomb(const void* __restrict__ Wc, const void* __restrict__ Wo,
                            const void* __restrict__ bo, const void* __restrict__ bc,
                            bf16* __restrict__ WcombHi, bf16* __restrict__ WcombLo,
                            float* __restrict__ beff, const int* __restrict__ flagp)
{
    const int f = *flagp;
    const int l = blockIdx.y, o = blockIdx.x, j = threadIdx.x;
    __shared__ float wcs[HID];
    const size_t rowc = (size_t)(l*HID + o) * 512;
    wcs[j] = ldf(Wc, rowc + HID + j, f);
    float c1 = ldf(Wc, rowc + j, f);
    { bf16 h = f2b(c1); WcombHi[rowc + j] = h; WcombLo[rowc + j] = f2b(c1 - b2f(h)); }
    __syncthreads();
    const size_t wbase = (size_t)l * HID * HID;
    float s = 0.f;
    for (int k = 0; k < HID; k++) s += wcs[k] * ldf(Wo, wbase + (size_t)k*HID + j, f);
    { bf16 h = f2b(s); WcombHi[rowc + HID + j] = h; WcombLo[rowc + HID + j] = f2b(s - b2f(h)); }
    if (j == 0) {
        float b = 0.f;
        for (int k = 0; k < HID; k++) b += wcs[k] * ldf(bo, l*HID + k, f);
        beff[l*HID + o] = b + ldf(bc, l*HID + o, f);
    }
}

// ---------------------------------------------------------------------------
// split-bf16 GEMM (input projection): C = A @ W^T + bias, dual-dtype in/out
// ---------------------------------------------------------------------------
#define GBK 32
#define GPAD 8

__global__ __launch_bounds__(256) void gemm_split(
    const void* __restrict__ Abase, size_t aoff, int lda,
    const bf16* __restrict__ Whi, const bf16* __restrict__ Wlo,
    const float* __restrict__ biasF,
    void* __restrict__ Cbase, size_t coff, int ldc, int cmode,
    const int* __restrict__ flagp)
{
    __shared__ short Ahi[128][GBK + GPAD], Alo[128][GBK + GPAD];
    __shared__ short Bhi[128][GBK + GPAD], Blo[128][GBK + GPAD];
    const int f = *flagp;
    const int tid  = threadIdx.x;
    const int lane = tid & 63;
    const int wave = tid >> 6;
    const int row0 = blockIdx.x * 128;
    const int col0 = blockIdx.y * 128;
    const int wr = (wave >> 1) * 64;
    const int wc = (wave & 1) * 64;
    const int q4  = lane >> 4;
    const int m16 = lane & 15;

    f32x4 acc[4][4];
    #pragma unroll
    for (int i = 0; i < 4; i++)
        #pragma unroll
        for (int j = 0; j < 4; j++)
            acc[i][j] = (f32x4){0.f,0.f,0.f,0.f};

    const int r0s = tid >> 2, s0s = tid & 3;
    const int r1s = r0s + 64;

    for (int k0 = 0; k0 < 256; k0 += GBK) {
        short8 h0, l0, h1, l1;
        load_split8(Abase, aoff + (size_t)(row0 + r0s)*lda + k0 + s0s*8, f, h0, l0);
        load_split8(Abase, aoff + (size_t)(row0 + r1s)*lda + k0 + s0s*8, f, h1, l1);
        *(short8*)&Ahi[r0s][s0s*8] = h0;  *(short8*)&Alo[r0s][s0s*8] = l0;
        *(short8*)&Ahi[r1s][s0s*8] = h1;  *(short8*)&Alo[r1s][s0s*8] = l1;
        *(short8*)&Bhi[r0s][s0s*8] = *(const short8*)(const void*)(Whi + (size_t)(col0 + r0s)*256 + k0 + s0s*8);
        *(short8*)&Blo[r0s][s0s*8] = *(const short8*)(const void*)(Wlo + (size_t)(col0 + r0s)*256 + k0 + s0s*8);
        *(short8*)&Bhi[r1s][s0s*8] = *(const short8*)(const void*)(Whi + (size_t)(col0 + r1s)*256 + k0 + s0s*8);
        *(short8*)&Blo[r1s][s0s*8] = *(const short8*)(const void*)(Wlo + (size_t)(col0 + r1s)*256 + k0 + s0s*8);
        __syncthreads();
        short8 ah[4], al[4], bh[4], bl[4];
        #pragma unroll
        for (int i = 0; i < 4; i++) {
            ah[i] = *(const short8*)&Ahi[wr + i*16 + m16][q4*8];
            al[i] = *(const short8*)&Alo[wr + i*16 + m16][q4*8];
        }
        #pragma unroll
        for (int j = 0; j < 4; j++) {
            bh[j] = *(const short8*)&Bhi[wc + j*16 + m16][q4*8];
            bl[j] = *(const short8*)&Blo[wc + j*16 + m16][q4*8];
        }
        #pragma unroll
        for (int i = 0; i < 4; i++)
            #pragma unroll
            for (int j = 0; j < 4; j++) {
                acc[i][j] = __builtin_amdgcn_mfma_f32_16x16x32_bf16(ah[i], bh[j], acc[i][j], 0, 0, 0);
                acc[i][j] = __builtin_amdgcn_mfma_f32_16x16x32_bf16(ah[i], bl[j], acc[i][j], 0, 0, 0);
                acc[i][j] = __builtin_amdgcn_mfma_f32_16x16x32_bf16(al[i], bh[j], acc[i][j], 0, 0, 0);
            }
        __syncthreads();
    }
    const bool outf32 = (cmode == 0) || f;
    #pragma unroll
    for (int j = 0; j < 4; j++) {
        int col = col0 + wc + j*16 + m16;
        float bj = biasF[col];
        #pragma unroll
        for (int i = 0; i < 4; i++)
            #pragma unroll
            for (int r = 0; r < 4; r++) {
                int row = row0 + wr + i*16 + q4*4 + r;
                float v = acc[i][j][r] + bj;
                if (outf32) ((float*)Cbase)[coff + (size_t)row*ldc + col] = v;
                else        ((bf16*)Cbase)[coff + (size_t)row*ldc + col] = f2b(v);
            }
    }
}

// ---------------------------------------------------------------------------
// batched level-0 K/V projection for all 3 layers: 6 GEMMs in one launch
// A = d_out rows 0..4095, chunk 0 (lda 1024); out f32 [4096,256]
// ---------------------------------------------------------------------------
struct KV0Args { const bf16* wh[6]; const bf16* wl[6]; const float* bs[6]; float* out[6]; };

__global__ __launch_bounds__(256) void gemm_kv0(
    const void* __restrict__ Abase, KV0Args a, const int* __restrict__ flagp)
{
    __shared__ short Ahi[128][GBK + GPAD], Alo[128][GBK + GPAD];
    __shared__ short Bhi[128][GBK + GPAD], Blo[128][GBK + GPAD];
    const int f = *flagp;
    const int z = blockIdx.z;
    const bf16* Whi = a.wh[z];
    const bf16* Wlo = a.wl[z];
    const float* biasF = a.bs[z];
    float* C = a.out[z];
    const int tid  = threadIdx.x;
    const int lane = tid & 63;
    const int wave = tid >> 6;
    const int row0 = blockIdx.x * 128;
    const int col0 = blockIdx.y * 128;
    const int wr = (wave >> 1) * 64;
    const int wc = (wave & 1) * 64;
    const int q4  = lane >> 4;
    const int m16 = lane & 15;

    f32x4 acc[4][4];
    #pragma unroll
    for (int i = 0; i < 4; i++)
        #pragma unroll
        for (int j = 0; j < 4; j++)
            acc[i][j] = (f32x4){0.f,0.f,0.f,0.f};

    const int r0s = tid >> 2, s0s = tid & 3;
    const int r1s = r0s + 64;

    for (int k0 = 0; k0 < 256; k0 += GBK) {
        short8 h0, l0, h1, l1;
        load_split8(Abase, (size_t)(row0 + r0s)*1024 + k0 + s0s*8, f, h0, l0);
        load_split8(Abase, (size_t)(row0 + r1s)*1024 + k0 + s0s*8, f, h1, l1);
        *(short8*)&Ahi[r0s][s0s*8] = h0;  *(short8*)&Alo[r0s][s0s*8] = l0;
        *(short8*)&Ahi[r1s][s0s*8] = h1;  *(short8*)&Alo[r1s][s0s*8] = l1;
        *(short8*)&Bhi[r0s][s0s*8] = *(const short8*)(const void*)(Whi + (size_t)(col0 + r0s)*256 + k0 + s0s*8);
        *(short8*)&Blo[r0s][s0s*8] = *(const short8*)(const void*)(Wlo + (size_t)(col0 + r0s)*256 + k0 + s0s*8);
        *(short8*)&Bhi[r1s][s0s*8] = *(const short8*)(const void*)(Whi + (size_t)(col0 + r1s)*256 + k0 + s0s*8);
        *(short8*)&Blo[r1s][s0s*8] = *(const short8*)(const void*)(Wlo + (size_t)(col0 + r1s)*256 + k0 + s0s*8);
        __syncthreads();
        short8 ah[4], al[4], bh[4], bl[4];
        #pragma unroll
        for (int i = 0; i < 4; i++) {
            ah[i] = *(const short8*)&Ahi[wr + i*16 + m16][q4*8];
            al[i] = *(const short8*)&Alo[wr + i*16 + m16][q4*8];
        }
        #pragma unroll
        for (int j = 0; j < 4; j++) {
            bh[j] = *(const short8*)&Bhi[wc + j*16 + m16][q4*8];
            bl[j] = *(const short8*)&Blo[wc + j*16 + m16][q4*8];
        }
        #pragma unroll
        for (int i = 0; i < 4; i++)
            #pragma unroll
            for (int j = 0; j < 4; j++) {
                acc[i][j] = __builtin_amdgcn_mfma_f32_16x16x32_bf16(ah[i], bh[j], acc[i][j], 0, 0, 0);
                acc[i][j] = __builtin_amdgcn_mfma_f32_16x16x32_bf16(ah[i], bl[j], acc[i][j], 0, 0, 0);
                acc[i][j] = __builtin_amdgcn_mfma_f32_16x16x32_bf16(al[i], bh[j], acc[i][j], 0, 0, 0);
            }
        __syncthreads();
    }
    #pragma unroll
    for (int j = 0; j < 4; j++) {
        int col = col0 + wc + j*16 + m16;
        float bj = biasF[col];
        #pragma unroll
        for (int i = 0; i < 4; i++)
            #pragma unroll
            for (int r = 0; r < 4; r++) {
                int row = row0 + wr + i*16 + q4*4 + r;
                C[(size_t)row*256 + col] = acc[i][j][r] + bj;
            }
    }
}

// out[r, 256..1024) = out[r, 0..256) for rows r < M
__global__ void replicate_l0(void* __restrict__ out, const int* __restrict__ flagp)
{
    const int f = *flagp;
    int idx = (blockIdx.x * 256 + threadIdx.x) * 8;
    int r = idx / 768, c = idx % 768;
    if (f) {
        float* o = (float*)out;
        f32x4 a = *(const f32x4*)(const void*)(o + (size_t)r*1024 + (c & 255));
        f32x4 b = *(const f32x4*)(const void*)(o + (size_t)r*1024 + (c & 255) + 4);
        *(f32x4*)(void*)(o + (size_t)r*1024 + 256 + c)     = a;
        *(f32x4*)(void*)(o + (size_t)r*1024 + 256 + c + 4) = b;
    } else {
        bf16* o = (bf16*)out;
        *(short8*)(void*)(o + (size_t)r*1024 + 256 + c) =
            *(const short8*)(const void*)(o + (size_t)r*1024 + (c & 255));
    }
}

// ---------------------------------------------------------------------------
// Diagonal wavefront step: one launch handles all tasks (l, lv) with l+lv==d.
// Each task: 256 blocks x 16 rows.  Per block:
//   qproj -> attention -> [prev|agg]@Wcomb + LN + GELU -> store h -> K/V proj
// ---------------------------------------------------------------------------
#define SRD 16
#define LROWB 264   // shorts (bf16 rows, +8 pad)
#define LROWF 260   // f32 rows, +4 pad

__global__ __launch_bounds__(256, 3) void step_diag(
    int d, int lmin,
    const int* __restrict__ preds,
    void* __restrict__ outb,
    const bf16* __restrict__ WqHi, const bf16* __restrict__ WqLo, const float* __restrict__ bqF,
    const bf16* __restrict__ WkHi, const bf16* __restrict__ WkLo, const float* __restrict__ bkF,
    const bf16* __restrict__ WvHi, const bf16* __restrict__ WvLo, const float* __restrict__ bvF,
    const bf16* __restrict__ WcombHi, const bf16* __restrict__ WcombLo, const float* __restrict__ beff,
    const float* __restrict__ lngF, const float* __restrict__ lnbF,
    float* __restrict__ arena,          // [K: 6 slots][V: 6 slots] of M*256 f32
    const int* __restrict__ flagp)
{
    __shared__ __align__(16) short prevHi[SRD][LROWB];
    __shared__ __align__(16) short prevLo[SRD][LROWB];
    __shared__ __align__(16) float fA[SRD][LROWF];   // qproj -> z -> h
    __shared__ __align__(16) float fB[SRD][LROWF];   // agg

    const int f = *flagp;
    const int t  = blockIdx.x >> 8;
    const int rb = blockIdx.x & 255;
    const int l  = lmin + t;
    const int lv = d - l;
    const int jbase = rb * SRD;

    const int tid  = threadIdx.x;
    const int lane = tid & 63;
    const int wave = tid >> 6;
    const int q4  = lane >> 4;
    const int m16 = lane & 15;
    const int cw  = wave * 64;

    const float* Kin = arena + (size_t)(l*2 + (lv & 1)) * MNODES * HID;
    const float* Vin = arena + (size_t)(6 + l*2 + (lv & 1)) * MNODES * HID;
    const size_t qoff = (size_t)(lv+1)*MNODES*1024 + (size_t)l*HID;
    const size_t hoff = (size_t)(lv+1)*MNODES*1024 + (size_t)(l+1)*HID;
    const int lb = l * HID;

    // ---- Phase 0: stage prev rows -> prevHi/prevLo ----
    #pragma unroll
    for (int s = 0; s < 4; s++) {
        int seg = s*256 + tid;
        int r = seg >> 6;
        int c = (seg & 63) * 4;
        size_t off = qoff + (size_t)(jbase + r)*1024 + c;
        if (f) {
            f32x4 v = *(const f32x4*)(const void*)((const float*)outb + off);
            #pragma unroll
            for (int e = 0; e < 4; e++) {
                short h = f2bs(v[e]);
                prevHi[r][c+e] = h;
                prevLo[r][c+e] = f2bs(v[e] - su2f(h));
            }
        } else {
            const short* p = (const short*)outb + off;
            #pragma unroll
            for (int e = 0; e < 4; e++) { prevHi[r][c+e] = p[e]; prevLo[r][c+e] = 0; }
        }
    }

    // ---- Phase 1: qproj = prev @ Wq^T + bq  -> fA (f32) ----
    {
        const bf16* WH = WqHi + (size_t)l*65536;
        const bf16* WL = WqLo + (size_t)l*65536;
        f32x4 acc[4];
        #pragma unroll
        for (int jj = 0; jj < 4; jj++) acc[jj] = (f32x4){0.f,0.f,0.f,0.f};
        __syncthreads();   // prev staged
        #pragma unroll
        for (int kk = 0; kk < 8; kk++) {
            short8 ah = *(const short8*)&prevHi[m16][kk*32 + q4*8];
            short8 al = *(const short8*)&prevLo[m16][kk*32 + q4*8];
            #pragma unroll
            for (int jj = 0; jj < 4; jj++) {
                short8 bh = *(const short8*)(const void*)(WH + (size_t)(cw + jj*16 + m16)*256 + kk*32 + q4*8);
                short8 bl = *(const short8*)(const void*)(WL + (size_t)(cw + jj*16 + m16)*256 + kk*32 + q4*8);
                acc[jj] = __builtin_amdgcn_mfma_f32_16x16x32_bf16(ah, bh, acc[jj], 0, 0, 0);
                acc[jj] = __builtin_amdgcn_mfma_f32_16x16x32_bf16(ah, bl, acc[jj], 0, 0, 0);
                acc[jj] = __builtin_amdgcn_mfma_f32_16x16x32_bf16(al, bh, acc[jj], 0, 0, 0);
            }
        }
        #pragma unroll
        for (int jj = 0; jj < 4; jj++) {
            int col = cw + jj*16 + m16;
            float bv_ = bqF[lb + col];
            #pragma unroll
            for (int r = 0; r < 4; r++)
                fA[q4*4 + r][col] = acc[jj][r] + bv_;
        }
    }
    __syncthreads();

    // ---- Phase 2: attention. 4 threads per (row,head), 16 dims each ----
    {
        const int part = tid & 3;
        const int rh   = tid >> 2;
        const int h    = rh & 3;
        const int r    = rh >> 2;
        const int j    = jbase + r;
        const int dbase = h*64 + part*16;

        float qf[16];
        #pragma unroll
        for (int e = 0; e < 4; e++) {
            f32x4 v = *(const f32x4*)(const void*)&fA[r][dbase + e*4];
            qf[e*4+0]=v[0]; qf[e*4+1]=v[1]; qf[e*4+2]=v[2]; qf[e*4+3]=v[3];
        }
        int pl[PRED];
        #pragma unroll
        for (int p = 0; p < PRED; p++)
            pl[p] = (preds[(size_t)lv*MNODES*PRED + (size_t)j*PRED + p] - lv*MNODES) & (MNODES-1);

        float sc[PRED];
        #pragma unroll
        for (int p = 0; p < PRED; p++) {
            const f32x4* kp = (const f32x4*)(const void*)(Kin + (size_t)pl[p]*HID + dbase);
            float s = 0.f;
            #pragma unroll
            for (int e = 0; e < 4; e++) {
                f32x4 v = kp[e];
                s += qf[e*4+0]*v[0] + qf[e*4+1]*v[1] + qf[e*4+2]*v[2] + qf[e*4+3]*v[3];
            }
            sc[p] = s;
        }
        #pragma unroll
        for (int p = 0; p < PRED; p++) {
            sc[p] += __shfl_xor(sc[p], 1);
            sc[p] += __shfl_xor(sc[p], 2);
            sc[p] *= 0.125f;
        }
        float mx = sc[0];
        #pragma unroll
        for (int p = 1; p < PRED; p++) mx = fmaxf(mx, sc[p]);
        float den = 0.f;
        #pragma unroll
        for (int p = 0; p < PRED; p++) { sc[p] = __expf(sc[p] - mx); den += sc[p]; }
        float inv = 1.f / den;

        float ag[16];
        #pragma unroll
        for (int e = 0; e < 16; e++) ag[e] = 0.f;
        #pragma unroll
        for (int p = 0; p < PRED; p++) {
            float wgt = sc[p] * inv;
            const f32x4* vp = (const f32x4*)(const void*)(Vin + (size_t)pl[p]*HID + dbase);
            #pragma unroll
            for (int e = 0; e < 4; e++) {
                f32x4 v = vp[e];
                ag[e*4+0] += wgt*v[0]; ag[e*4+1] += wgt*v[1];
                ag[e*4+2] += wgt*v[2]; ag[e*4+3] += wgt*v[3];
            }
        }
        #pragma unroll
        for (int e = 0; e < 4; e++) {
            f32x4 v = {ag[e*4+0], ag[e*4+1], ag[e*4+2], ag[e*4+3]};
            *(f32x4*)(void*)&fB[r][dbase + e*4] = v;
        }
    }
    __syncthreads();

    // ---- Phase 3: z = [prev|agg] @ Wcomb^T + beff -> fA (f32) ----
    {
        const bf16* WH = WcombHi + (size_t)l*131072;
        const bf16* WL = WcombLo + (size_t)l*131072;
        f32x4 acc[4];
        #pragma unroll
        for (int jj = 0; jj < 4; jj++) acc[jj] = (f32x4){0.f,0.f,0.f,0.f};
        #pragma unroll
        for (int kk = 0; kk < 8; kk++) {   // q half (k in [0,256))
            short8 ah = *(const short8*)&prevHi[m16][kk*32 + q4*8];
            short8 al = *(const short8*)&prevLo[m16][kk*32 + q4*8];
            #pragma unroll
            for (int jj = 0; jj < 4; jj++) {
                short8 bh = *(const short8*)(const void*)(WH + (size_t)(cw + jj*16 + m16)*512 + kk*32 + q4*8);
                short8 bl = *(const short8*)(const void*)(WL + (size_t)(cw + jj*16 + m16)*512 + kk*32 + q4*8);
                acc[jj] = __builtin_amdgcn_mfma_f32_16x16x32_bf16(ah, bh, acc[jj], 0, 0, 0);
                acc[jj] = __builtin_amdgcn_mfma_f32_16x16x32_bf16(ah, bl, acc[jj], 0, 0, 0);
                acc[jj] = __builtin_amdgcn_mfma_f32_16x16x32_bf16(al, bh, acc[jj], 0, 0, 0);
            }
        }
        #pragma unroll
        for (int kk = 0; kk < 8; kk++) {   // agg half (k in [256,512))
            short8 ah, al;
            split8_f32(&fB[m16][kk*32 + q4*8], ah, al);
            #pragma unroll
            for (int jj = 0; jj < 4; jj++) {
                short8 bh = *(const short8*)(const void*)(WH + (size_t)(cw + jj*16 + m16)*512 + 256 + kk*32 + q4*8);
                short8 bl = *(const short8*)(const void*)(WL + (size_t)(cw + jj*16 + m16)*512 + 256 + kk*32 + q4*8);
                acc[jj] = __builtin_amdgcn_mfma_f32_16x16x32_bf16(ah, bh, acc[jj], 0, 0, 0);
                acc[jj] = __builtin_amdgcn_mfma_f32_16x16x32_bf16(ah, bl, acc[jj], 0, 0, 0);
                acc[jj] = __builtin_amdgcn_mfma_f32_16x16x32_bf16(al, bh, acc[jj], 0, 0, 0);
            }
        }
        #pragma unroll
        for (int jj = 0; jj < 4; jj++) {
            int col = cw + jj*16 + m16;
            float be = beff[lb + col];
            #pragma unroll
            for (int r = 0; r < 4; r++)
                fA[q4*4 + r][col] = acc[jj][r] + be;
        }
    }
    __syncthreads();

    // ---- Phase 4: LayerNorm + GELU in fA (16 threads/row) ----
    {
        const int rr = tid >> 4;
        const int g  = tid & 15;
        float sum = 0.f, sq = 0.f;
        #pragma unroll
        for (int c = 0; c < 16; c++) {
            float z = fA[rr][g + 16*c];
            sum += z; sq += z*z;
        }
        sum += __shfl_xor(sum, 1); sq += __shfl_xor(sq, 1);
        sum += __shfl_xor(sum, 2); sq += __shfl_xor(sq, 2);
        sum += __shfl_xor(sum, 4); sq += __shfl_xor(sq, 4);
        sum += __shfl_xor(sum, 8); sq += __shfl_xor(sq, 8);
        float mean = sum * (1.f/256.f);
        float var  = fmaxf(sq * (1.f/256.f) - mean*mean, 0.f);
        float rstd = rsqrtf(var + LN_EPS);
        #pragma unroll
        for (int c = 0; c < 16; c++) {
            int col = g + 16*c;
            float zn = (fA[rr][col] - mean) * rstd * lngF[lb + col] + lnbF[lb + col];
            fA[rr][col] = 0.5f * zn * (1.f + erff(zn * 0.70710678118f));
        }
    }
    __syncthreads();

    // ---- Phase 5: store h -> d_out chunk l+1 ----
    {
        const int rr = tid >> 4;
        const int g  = tid & 15;
        size_t off = hoff + (size_t)(jbase + rr)*1024 + g*16;
        if (f) {
            float* dst = (float*)outb + off;
            #pragma unroll
            for (int e = 0; e < 4; e++)
                *(f32x4*)(void*)(dst + e*4) = *(const f32x4*)(const void*)&fA[rr][g*16 + e*4];
        } else {
            bf16* dst = (bf16*)outb + off;
            #pragma unroll
            for (int s = 0; s < 2; s++) {
                short8 o;
                #pragma unroll
                for (int e = 0; e < 8; e++) o[e] = f2bs(fA[rr][g*16 + s*8 + e]);
                *(short8*)(void*)(dst + s*8) = o;
            }
        }
    }

    // ---- Phase 6: next-level K/V projections ----
    if (lv < 14) {
        #pragma unroll
        for (int pass = 0; pass < 2; pass++) {
            const bf16* WH = (pass ? WvHi : WkHi) + (size_t)l*65536;
            const bf16* WL = (pass ? WvLo : WkLo) + (size_t)l*65536;
            const float* bp = (pass ? bvF : bkF) + lb;
            float* Op = arena + (size_t)((pass ? 6 : 0) + l*2 + ((lv+1) & 1)) * MNODES * HID;
            f32x4 acc[4];
            #pragma unroll
            for (int jj = 0; jj < 4; jj++) acc[jj] = (f32x4){0.f,0.f,0.f,0.f};
            #pragma unroll
            for (int kk = 0; kk < 8; kk++) {
                short8 ah, al;
                split8_f32(&fA[m16][kk*32 + q4*8], ah, al);
                #pragma unroll
                for (int jj = 0; jj < 4; jj++) {
                    short8 bh = *(const short8*)(const void*)(WH + (size_t)(cw + jj*16 + m16)*256 + kk*32 + q4*8);
                    short8 bl = *(const short8*)(const void*)(WL + (size_t)(cw + jj*16 + m16)*256 + kk*32 + q4*8);
                    acc[jj] = __builtin_amdgcn_mfma_f32_16x16x32_bf16(ah, bh, acc[jj], 0, 0, 0);
                    acc[jj] = __builtin_amdgcn_mfma_f32_16x16x32_bf16(ah, bl, acc[jj], 0, 0, 0);
                    acc[jj] = __builtin_amdgcn_mfma_f32_16x16x32_bf16(al, bh, acc[jj], 0, 0, 0);
                }
            }
            #pragma unroll
            for (int jj = 0; jj < 4; jj++) {
                int col = cw + jj*16 + m16;
                float bb = bp[col];
                #pragma unroll
                for (int r = 0; r < 4; r++)
                    Op[(size_t)(jbase + q4*4 + r)*HID + col] = acc[jj][r] + bb;
            }
        }
    }
}

// ---------------------------------------------------------------------------
extern "C" void kernel_launch(void* const* d_in, const int* in_sizes, int n_in,
                              void* d_out, int out_size, void* d_ws, size_t ws_size,
                              hipStream_t stream)
{
    (void)in_sizes; (void)n_in; (void)out_size; (void)ws_size;
    const void* x    = d_in[0];
    const int* preds = (const int*)d_in[3];
    const void* W_in = d_in[4];  const void* b_in = d_in[5];
    const void* Wq   = d_in[6];  const void* bq   = d_in[7];
    const void* Wk   = d_in[8];  const void* bk   = d_in[9];
    const void* Wv   = d_in[10]; const void* bv   = d_in[11];
    const void* Wo   = d_in[12]; const void* bo   = d_in[13];
    const void* Wc   = d_in[14]; const void* bc   = d_in[15];
    const void* lng  = d_in[16]; const void* lnb  = d_in[17];

    char* w = (char*)d_ws;
    #define TAKE(T, nbytes) (T*)w; w += (((size_t)(nbytes)) + 255) & ~(size_t)255
    int*   flag  = TAKE(int,   4);
    float* beff  = TAKE(float, 3*HID*4);
    float* binF  = TAKE(float, HID*4);
    float* bqF   = TAKE(float, 3*HID*4);
    float* bkF   = TAKE(float, 3*HID*4);
    float* bvF   = TAKE(float, 3*HID*4);
    float* lngF  = TAKE(float, 3*HID*4);
    float* lnbF  = TAKE(float, 3*HID*4);
    bf16* WinHi  = TAKE(bf16, 65536*2);   bf16* WinLo = TAKE(bf16, 65536*2);
    bf16* WqHi   = TAKE(bf16, 196608*2);  bf16* WqLo  = TAKE(bf16, 196608*2);
    bf16* WkHi   = TAKE(bf16, 196608*2);  bf16* WkLo  = TAKE(bf16, 196608*2);
    bf16* WvHi   = TAKE(bf16, 196608*2);  bf16* WvLo  = TAKE(bf16, 196608*2);
    bf16* WcombHi= TAKE(bf16, 393216*2);  bf16* WcombLo = TAKE(bf16, 393216*2);
    float* arena = TAKE(float, (size_t)12 * MNODES * HID * 4);   // 48 MB
    #undef TAKE

    detect_dtype<<<1, 256, 0, stream>>>((const unsigned short*)x, flag);

    CA ca;
    ca.d[0] = {W_in, WinHi, WinLo, nullptr, 65536, 0};
    ca.d[1] = {Wq,   WqHi,  WqLo,  nullptr, 196608, 0};
    ca.d[2] = {Wk,   WkHi,  WkLo,  nullptr, 196608, 0};
    ca.d[3] = {Wv,   WvHi,  WvLo,  nullptr, 196608, 0};
    ca.d[4] = {b_in, nullptr, nullptr, binF, 256, 1};
    ca.d[5] = {bq,   nullptr, nullptr, bqF,  768, 1};
    ca.d[6] = {bk,   nullptr, nullptr, bkF,  768, 1};
    ca.d[7] = {bv,   nullptr, nullptr, bvF,  768, 1};
    ca.d[8] = {lng,  nullptr, nullptr, lngF, 768, 1};
    ca.d[9] = {lnb,  nullptr, nullptr, lnbF, 768, 1};
    convert_in<<<dim3(96, 10), 256, 0, stream>>>(ca, flag);

    build_wcomb<<<dim3(HID, 3), 256, 0, stream>>>(Wc, Wo, bo, bc, WcombHi, WcombLo, beff, flag);

    // input projection -> d_out chunk 0, all 65536 rows
    gemm_split<<<dim3(NTOT/128, 2), 256, 0, stream>>>(x, 0, HID, WinHi, WinLo, binF,
                                                      d_out, 0, 1024, 1, flag);
    replicate_l0<<<(MNODES*768/8)/256, 256, 0, stream>>>(d_out, flag);

    // level-0 K/V for all 3 layers, one batched launch
    KV0Args kv;
    for (int l = 0; l < 3; l++) {
        kv.wh[l*2+0] = WkHi + (size_t)l*65536;  kv.wl[l*2+0] = WkLo + (size_t)l*65536;
        kv.bs[l*2+0] = bkF + l*HID;
        kv.out[l*2+0] = arena + (size_t)(l*2 + 0) * MNODES * HID;
        kv.wh[l*2+1] = WvHi + (size_t)l*65536;  kv.wl[l*2+1] = WvLo + (size_t)l*65536;
        kv.bs[l*2+1] = bvF + l*HID;
        kv.out[l*2+1] = arena + (size_t)(6 + l*2 + 0) * MNODES * HID;
    }
    gemm_kv0<<<dim3(MNODES/128, 2, 6), 256, 0, stream>>>(d_out, kv, flag);

    // wavefront over diagonals d = l + lv
    for (int d = 0; d <= 16; d++) {
        int lmin = (d > 14) ? (d - 14) : 0;
        int lmax = (d < 2) ? d : 2;
        int nt = lmax - lmin + 1;
        step_diag<<<dim3(nt * 256), 256, 0, stream>>>(
            d, lmin, preds, d_out,
            WqHi, WqLo, bqF,
            WkHi, WkLo, bkF,
            WvHi, WvLo, bvF,
            WcombHi, WcombLo, beff,
            lngF, lnbF,
            arena, flag);
    }
}